// Round 8
// baseline (929.002 us; speedup 1.0000x reference)
//
#include <hip/hip_runtime.h>

#define N_TRAIN 100000
#define DIM 768
#define NQ 1024
#define BN 48                  // cols per chunk; LDS 74KB -> 2 WGs/CU
#define NCHUNK 2084            // ceil(100000/48), tail chunk has 16 valid
#define MARGIN 6.0f
#define MAXC 65536

typedef __bf16 bf16x8 __attribute__((ext_vector_type(8)));
typedef float f32x4 __attribute__((ext_vector_type(4)));
typedef unsigned short u16x8 __attribute__((ext_vector_type(8)));

__device__ __forceinline__ unsigned short f2bf(float f) {
  unsigned int u = __builtin_bit_cast(unsigned int, f);
  u = (u + 0x7FFFu + ((u >> 16) & 1u)) >> 16;   // RNE fp32->bf16
  return (unsigned short)u;
}
__device__ __forceinline__ float bf2f(unsigned short h) {
  return __builtin_bit_cast(float, (unsigned int)h << 16);
}
// monotonic float<->uint for atomicMin over possibly-negative floats
__device__ __forceinline__ unsigned int fenc(float f) {
  unsigned int u = __builtin_bit_cast(unsigned int, f);
  return (u & 0x80000000u) ? ~u : (u | 0x80000000u);
}
__device__ __forceinline__ float fdec(unsigned int u) {
  u = (u & 0x80000000u) ? (u & 0x7FFFFFFFu) : ~u;
  return __builtin_bit_cast(float, u);
}

// ---------------- init ----------------
__global__ void initK(unsigned long long* res, unsigned int* gmin, unsigned int* cnt) {
  int t = threadIdx.x;
  res[t] = ~0ull;
  gmin[t] = 0xFFFFFFFFu;
  if (t == 0) *cnt = 0u;
}

// ------- convert queries to bf16, pre-swizzled MFMA A-fragment layout -------
// mfma_f32_16x16x32_bf16 A-operand: lane l -> row=l&15, k=(l>>4)*8..+7
// Asw[fragid=mf*24+ks][lane][8 bf16] -> coalesced 1KB wave loads, L2-resident
__global__ void convA(const float* __restrict__ x, unsigned short* __restrict__ Asw) {
  int t = blockIdx.x * 256 + threadIdx.x;   // 0..98303
  int l = t & 63;
  int fragid = t >> 6;                      // 0..1535
  int mf = fragid / 24;
  int ks = fragid - mf * 24;
  int row = mf * 16 + (l & 15);
  int k = ks * 32 + (l >> 4) * 8;
  const float* src = x + (size_t)row * DIM + k;
  u16x8 h;
#pragma unroll
  for (int i = 0; i < 8; ++i) h[i] = f2bf(src[i]);
  *(u16x8*)(Asw + (size_t)fragid * 512 + l * 8) = h;
}

// ---------------- Pass A: approx bf16 GEMM + block-min ----------------
// One WG per 48-column chunk. B-tile (full K=768) staged ONCE in 74KB LDS
// (bf16, XOR-swizzled); k-loop is a manual 1-deep software pipeline
// (even/odd prefetch regs) so L2 A-frag latency hides under MFMAs.
// SWIZZLE RULE: XOR must apply to the FINAL address (add ks*32 first, then
// ^mask) — mask bits 3-5 overlap the ks*32 addend (R7 bug).
// NOTE: full #pragma unroll of the k-loop spills to scratch (R2-R5's hidden
// 1.1GB write traffic). Keep the pipeline manual, watch WRITE_SIZE for spill.
__global__ __launch_bounds__(512, 4) void passA(
    const float* __restrict__ Xt, const unsigned short* __restrict__ Asw,
    float* __restrict__ bmin, int fine) {
  __shared__ __align__(16) unsigned short Bs[BN * DIM];  // 73728 B
  __shared__ float t2p[BN][8];
  __shared__ float t2s[BN];
  const int tid = threadIdx.x;
  const int chunk = blockIdx.x;

  // ---- stage: 48 train rows -> bf16 LDS (swizzled) + sum-of-squares ----
  if (tid < 384) {
    const int c = tid >> 3;      // local column (train row) 0..47
    const int sl = tid & 7;      // k-slice
    const int n = chunk * BN + c;
    float ss = 0.f;
    if (n < N_TRAIN) {
      const float* src = Xt + (size_t)n * DIM + sl * 8;
#pragma unroll
      for (int j = 0; j < 12; ++j) {
        f32x4 v0 = *(const f32x4*)(src + j * 64);
        f32x4 v1 = *(const f32x4*)(src + j * 64 + 4);
        u16x8 h;
        h[0] = f2bf(v0[0]); h[1] = f2bf(v0[1]); h[2] = f2bf(v0[2]); h[3] = f2bf(v0[3]);
        h[4] = f2bf(v1[0]); h[5] = f2bf(v1[1]); h[6] = f2bf(v1[2]); h[7] = f2bf(v1[3]);
#pragma unroll
        for (int i = 0; i < 8; ++i) { float f = bf2f(h[i]); ss = fmaf(f, f, ss); }
        int e = (c * DIM + sl * 8 + j * 64) ^ ((c & 7) << 3);
        *(u16x8*)(&Bs[e]) = h;
      }
    } else {
      u16x8 h;
#pragma unroll
      for (int i = 0; i < 8; ++i) h[i] = 0;
#pragma unroll
      for (int j = 0; j < 12; ++j) {
        int e = (c * DIM + sl * 8 + j * 64) ^ ((c & 7) << 3);
        *(u16x8*)(&Bs[e]) = h;
      }
    }
    t2p[c][sl] = ss;
  }
  __syncthreads();
  if (tid < BN) {
    float s = 0.f;
#pragma unroll
    for (int j = 0; j < 8; ++j) s += t2p[tid][j];
    t2s[tid] = (chunk * BN + tid < N_TRAIN) ? s : 3.0e38f;
  }
  __syncthreads();

  const int wid = tid >> 6;
  const int l = tid & 63;
  const int lc = l & 15;
  const int lg = l >> 4;

  // per-lane invariant bases (UNswizzled) + XOR masks applied after +ks*32
  int cb0, cb1, cb2, xm0, xm1, xm2;
  {
    int c0 = 0 * 16 + lc, c1 = 1 * 16 + lc, c2 = 2 * 16 + lc;
    cb0 = c0 * DIM + lg * 8;  xm0 = (c0 & 7) << 3;
    cb1 = c1 * DIM + lg * 8;  xm1 = (c1 & 7) << 3;
    cb2 = c2 * DIM + lg * 8;  xm2 = (c2 & 7) << 3;
  }

  for (int mt = 0; mt < 2; ++mt) {          // 2 m-tiles of 512 query rows
    f32x4 acc[4][3];
#pragma unroll
    for (int rf = 0; rf < 4; ++rf)
#pragma unroll
      for (int cf = 0; cf < 3; ++cf) {
        acc[rf][cf][0] = 0.f; acc[rf][cf][1] = 0.f;
        acc[rf][cf][2] = 0.f; acc[rf][cf][3] = 0.f;
      }
    const int mfbase = mt * 32 + wid * 4;   // wave owns 64 query rows = 4 row-frags
    const unsigned short* ap = Asw + (size_t)(mfbase * 24) * 512 + l * 8;

    bf16x8 a[4], b[3], a2[4], b2[3];
    // prologue: load ks=0
#pragma unroll
    for (int rf = 0; rf < 4; ++rf)
      a[rf] = __builtin_bit_cast(bf16x8, *(const u16x8*)(ap + (rf * 24 + 0) * 512));
    b[0] = __builtin_bit_cast(bf16x8, *(const u16x8*)(&Bs[cb0 ^ xm0]));
    b[1] = __builtin_bit_cast(bf16x8, *(const u16x8*)(&Bs[cb1 ^ xm1]));
    b[2] = __builtin_bit_cast(bf16x8, *(const u16x8*)(&Bs[cb2 ^ xm2]));

    for (int ks = 0; ks < 24; ks += 2) {    // even/odd 1-deep pipeline
      // prefetch ks+1 into (a2,b2)
      int k1 = ks + 1;
#pragma unroll
      for (int rf = 0; rf < 4; ++rf)
        a2[rf] = __builtin_bit_cast(bf16x8, *(const u16x8*)(ap + (rf * 24 + k1) * 512));
      b2[0] = __builtin_bit_cast(bf16x8, *(const u16x8*)(&Bs[(cb0 + k1 * 32) ^ xm0]));
      b2[1] = __builtin_bit_cast(bf16x8, *(const u16x8*)(&Bs[(cb1 + k1 * 32) ^ xm1]));
      b2[2] = __builtin_bit_cast(bf16x8, *(const u16x8*)(&Bs[(cb2 + k1 * 32) ^ xm2]));
      // compute ks
#pragma unroll
      for (int rf = 0; rf < 4; ++rf)
#pragma unroll
        for (int cf = 0; cf < 3; ++cf)
          acc[rf][cf] = __builtin_amdgcn_mfma_f32_16x16x32_bf16(a[rf], b[cf], acc[rf][cf], 0, 0, 0);
      // prefetch ks+2 into (a,b) (last iter: harmless reload of ks=0)
      int k2 = (ks + 2 < 24) ? ks + 2 : 0;
#pragma unroll
      for (int rf = 0; rf < 4; ++rf)
        a[rf] = __builtin_bit_cast(bf16x8, *(const u16x8*)(ap + (rf * 24 + k2) * 512));
      b[0] = __builtin_bit_cast(bf16x8, *(const u16x8*)(&Bs[(cb0 + k2 * 32) ^ xm0]));
      b[1] = __builtin_bit_cast(bf16x8, *(const u16x8*)(&Bs[(cb1 + k2 * 32) ^ xm1]));
      b[2] = __builtin_bit_cast(bf16x8, *(const u16x8*)(&Bs[(cb2 + k2 * 32) ^ xm2]));
      // compute ks+1
#pragma unroll
      for (int rf = 0; rf < 4; ++rf)
#pragma unroll
        for (int cf = 0; cf < 3; ++cf)
          acc[rf][cf] = __builtin_amdgcn_mfma_f32_16x16x32_bf16(a2[rf], b2[cf], acc[rf][cf], 0, 0, 0);
    }

    // ---- epilogue: d2' = t2 - 2*cross ; per-row mins; contiguous writes ----
    const int rowbase = mt * 512 + wid * 64;
#pragma unroll
    for (int rf = 0; rf < 4; ++rf) {
#pragma unroll
      for (int reg = 0; reg < 4; ++reg) {
        int row = rowbase + rf * 16 + lg * 4 + reg;
        if (fine) {                           // 3 blocks of 16 cols
#pragma unroll
          for (int cf = 0; cf < 3; ++cf) {
            float v = t2s[cf * 16 + lc] - 2.f * acc[rf][cf][reg];
#pragma unroll
            for (int s = 1; s < 16; s <<= 1) v = fminf(v, __shfl_xor(v, s));
            if (lc == 0)
              bmin[(size_t)chunk * (NQ * 3) + row * 3 + cf] = v;
          }
        } else {                              // one block of 48 cols
          float v = 3.0e38f;
#pragma unroll
          for (int cf = 0; cf < 3; ++cf)
            v = fminf(v, t2s[cf * 16 + lc] - 2.f * acc[rf][cf][reg]);
#pragma unroll
          for (int s = 1; s < 16; s <<= 1) v = fminf(v, __shfl_xor(v, s));
          if (lc == 0)
            bmin[(size_t)chunk * NQ + row] = v;
        }
      }
    }
  }
}

// ------- Pass B1: per-query global min (coalesced over q, atomicMin) -------
__global__ __launch_bounds__(256) void passB1(const float* __restrict__ bmin,
                                              unsigned int* __restrict__ gmin, int bpq) {
  int qg = blockIdx.x >> 4, cs = blockIdx.x & 15;
  int w = threadIdx.x >> 6, l = threadIdx.x & 63;
  int q = qg * 64 + l;
  float m = 3.0e38f;
  for (int j = cs * 4 + w; j < NCHUNK; j += 64) {
    const float* p = bmin + (size_t)j * (NQ * bpq) + q * bpq;
    for (int cf = 0; cf < bpq; ++cf) m = fminf(m, p[cf]);
  }
  __shared__ float sm[4][64];
  sm[w][l] = m;
  __syncthreads();
  if (threadIdx.x < 64) {
    float v = fminf(fminf(sm[0][l], sm[1][l]), fminf(sm[2][l], sm[3][l]));
    atomicMin(&gmin[q], fenc(v));
  }
}

// ------- Pass B2: emit candidate blocks within min+MARGIN -------
__global__ __launch_bounds__(256) void passB2(const float* __restrict__ bmin,
                                              const unsigned int* __restrict__ gmin,
                                              unsigned int* __restrict__ cnt,
                                              unsigned int* __restrict__ cand, int bpq) {
  int qg = blockIdx.x >> 4, cs = blockIdx.x & 15;
  int w = threadIdx.x >> 6, l = threadIdx.x & 63;
  int q = qg * 64 + l;
  float thr = fdec(gmin[q]) + MARGIN;
  for (int j = cs * 4 + w; j < NCHUNK; j += 64) {
    const float* p = bmin + (size_t)j * (NQ * bpq) + q * bpq;
    for (int cf = 0; cf < bpq; ++cf) {
      if (p[cf] <= thr) {
        unsigned int pos = atomicAdd(cnt, 1u);
        if (pos < MAXC) cand[pos] = ((unsigned int)q << 16) | (unsigned int)(j * bpq + cf);
      }
    }
  }
}

// ---------------- Pass C: exact fp32 re-rank of candidates ----------------
__global__ void passC(const float* __restrict__ x, const float* __restrict__ Xt,
                      const unsigned int* __restrict__ cnt, const unsigned int* __restrict__ cand,
                      unsigned long long* __restrict__ res, int cpbsh, int ncols) {
  unsigned int count = *cnt;
  if (count > MAXC) count = MAXC;
  int w = threadIdx.x >> 6, l = threadIdx.x & 63;
  long pairs = (long)count << cpbsh;
  for (long p = (long)blockIdx.x * 4 + w; p < pairs; p += (long)gridDim.x * 4) {
    unsigned int cd = cand[p >> cpbsh];
    int q = cd >> 16;
    int blk = cd & 0xFFFF;
    int col = (int)(p & ((1 << cpbsh) - 1));
    int n = blk * ncols + col;
    if (col >= ncols || n >= N_TRAIN) continue;   // wave-uniform
    const float* xq = x + (size_t)q * DIM;
    const float* tn = Xt + (size_t)n * DIM;
    float s = 0.f;
#pragma unroll
    for (int i = 0; i < 12; ++i) {
      float d = xq[i * 64 + l] - tn[i * 64 + l];
      s = fmaf(d, d, s);
    }
#pragma unroll
    for (int sh = 1; sh < 64; sh <<= 1) s += __shfl_xor(s, sh);
    if (l == 0) {
      unsigned long long key =
          ((unsigned long long)__builtin_bit_cast(unsigned int, s) << 32) | (unsigned int)n;
      atomicMin(res + q, key);                // min d2, tie -> lowest index
    }
  }
}

// ---------------- Pass D: gather ----------------
__global__ void passD(const unsigned long long* __restrict__ res,
                      const float* __restrict__ Y, float* __restrict__ out) {
  int t = blockIdx.x * 256 + threadIdx.x;
  if (t < NQ * 24) {
    int q = t / 24, j = t - q * 24;
    unsigned int idx = (unsigned int)(res[q] & 0xFFFFFFFFu);
    out[t] = Y[(size_t)idx * 24 + j];
  }
}

extern "C" void kernel_launch(void* const* d_in, const int* in_sizes, int n_in,
                              void* d_out, int out_size, void* d_ws, size_t ws_size,
                              hipStream_t stream) {
  const float* x  = (const float*)d_in[0];   // [1024][768]
  const float* Xt = (const float*)d_in[1];   // [100000][768]
  const float* Y  = (const float*)d_in[2];   // [100000][24]
  float* out = (float*)d_out;                // [1024*24]
  char* ws = (char*)d_ws;
  unsigned long long* res  = (unsigned long long*)(ws);        // 8192 B
  unsigned int*       cnt  = (unsigned int*)(ws + 8192);       // 256 B
  unsigned int*       gmin = (unsigned int*)(ws + 8448);       // 4096 B
  unsigned int*       cand = (unsigned int*)(ws + 12544);      // 256 KB
  unsigned short*     Asw  = (unsigned short*)(ws + 274688);   // 1.5 MB
  float*              bmin = (float*)(ws + 1847552);           // 25.6 / 8.5 MB

  size_t needFine = 1847552ull + (size_t)NCHUNK * NQ * 3 * 4ull;  // ~27.5 MB
  int fine, bpq, cpbsh, ncols;
  if (ws_size >= needFine) { fine = 1; bpq = 3; cpbsh = 4; ncols = 16; }
  else                     { fine = 0; bpq = 1; cpbsh = 6; ncols = 48; }

  hipLaunchKernelGGL(initK,  dim3(1),      dim3(1024), 0, stream, res, gmin, cnt);
  hipLaunchKernelGGL(convA,  dim3(384),    dim3(256),  0, stream, x, Asw);
  hipLaunchKernelGGL(passA,  dim3(NCHUNK), dim3(512),  0, stream, Xt, Asw, bmin, fine);
  hipLaunchKernelGGL(passB1, dim3(256),    dim3(256),  0, stream, bmin, gmin, bpq);
  hipLaunchKernelGGL(passB2, dim3(256),    dim3(256),  0, stream, bmin, gmin, cnt, cand, bpq);
  hipLaunchKernelGGL(passC,  dim3(512),    dim3(256),  0, stream, x, Xt, cnt, cand, res, cpbsh, ncols);
  hipLaunchKernelGGL(passD,  dim3(96),     dim3(256),  0, stream, res, Y, out);
}

// Round 9
// 529.668 us; speedup vs baseline: 1.7539x; 1.7539x over previous
//
#include <hip/hip_runtime.h>

#define N_TRAIN 100000
#define DIM 768
#define NQ 1024
#define BN 96                  // cols per chunk (fp8); LDS ~78KB -> 2 WGs/CU
#define NCHUNK 1042            // ceil(100000/96), tail chunk has 64 valid
#define MARGIN 36.0f           // d2 margin for fp8 filter (~6.3 sigma)
#define MAXC 65536

typedef float f32x4 __attribute__((ext_vector_type(4)));
typedef unsigned long long u64;
typedef u64 u64x2 __attribute__((ext_vector_type(2)));

// ---- manual fp32 <-> OCP e4m3 (RNE); same fn for A and B => consistent ----
__device__ __forceinline__ unsigned char f2q(float f) {
  unsigned int u = __builtin_bit_cast(unsigned int, f);
  unsigned int s = (u >> 24) & 0x80u;
  int e = (int)((u >> 23) & 0xFFu) - 127;
  unsigned int m = u & 0x7FFFFFu;
  if (e < -9) return (unsigned char)s;          // underflow -> +-0
  if (e < -6) {                                  // fp8 subnormal
    int rb = 20 + (-6 - e);                      // 21..23
    unsigned int full = 0x800000u | m;
    unsigned int q = full >> rb;
    unsigned int rem = full & ((1u << rb) - 1u);
    unsigned int half = 1u << (rb - 1);
    q += (rem > half) || (rem == half && (q & 1u));
    return (unsigned char)(s | q);               // q<=8 rolls into min normal
  }
  unsigned int q = m >> 20;
  unsigned int rem = m & 0xFFFFFu;
  q += (rem > 0x80000u) || (rem == 0x80000u && (q & 1u));
  int ee = e + 7;
  if (q == 8u) { q = 0u; ee += 1; }
  if (ee >= 16) return (unsigned char)(s | 0x7Eu);  // clamp 448 (unreachable here)
  return (unsigned char)(s | ((unsigned)ee << 3) | q);
}
__device__ __forceinline__ float q2f(unsigned char h) {
  unsigned int s = ((unsigned int)h & 0x80u) << 24;
  int ee = (h >> 3) & 15; unsigned int m = h & 7u;
  if (ee == 0) {
    float v = (float)m * 0.001953125f;           // m * 2^-9
    return __builtin_bit_cast(float, s | __builtin_bit_cast(unsigned int, v));
  }
  return __builtin_bit_cast(float, s | ((unsigned int)(ee + 120) << 23) | (m << 20));
}
// monotonic float<->uint for atomicMin over possibly-negative floats
__device__ __forceinline__ unsigned int fenc(float f) {
  unsigned int u = __builtin_bit_cast(unsigned int, f);
  return (u & 0x80000000u) ? ~u : (u | 0x80000000u);
}
__device__ __forceinline__ float fdec(unsigned int u) {
  u = (u & 0x80000000u) ? (u & 0x7FFFFFFFu) : ~u;
  return __builtin_bit_cast(float, u);
}

// ---------------- init ----------------
__global__ void initK(unsigned long long* res, unsigned int* gmin, unsigned int* cnt) {
  int t = threadIdx.x;
  res[t] = ~0ull;
  gmin[t] = 0xFFFFFFFFu;
  if (t == 0) *cnt = 0u;
}

// ------- convert queries to fp8, pre-swizzled MFMA A-fragment layout -------
// mfma 16x16x32 A-operand: lane l -> row=l&15, k=(l>>4)*8..+7 (8 fp8 = 8B)
// Asw[fragid=mf*24+ks][lane][8B] -> coalesced 512B wave loads, L2-resident
__global__ void convA(const float* __restrict__ x, unsigned char* __restrict__ Asw) {
  int t = blockIdx.x * 256 + threadIdx.x;   // 0..98303
  int l = t & 63;
  int fragid = t >> 6;                      // 0..1535 (64 mf x 24 ks)
  int mf = fragid / 24;
  int ks = fragid - mf * 24;
  int row = mf * 16 + (l & 15);
  int k = ks * 32 + (l >> 4) * 8;
  const float* src = x + (size_t)row * DIM + k;
  u64 v = 0;
#pragma unroll
  for (int i = 0; i < 8; ++i) v |= (u64)f2q(src[i]) << (8 * i);
  *(u64*)(Asw + (size_t)fragid * 512 + l * 8) = v;
}

// ---------------- Pass A: fp8 filter GEMM + block-min ----------------
// One WG per 96-col chunk; B (full K=768, fp8) staged once in 72KB LDS
// (XOR-swizzled, 16B granules). Rolled k-loop: 2 A-loads(8B) + 6 ds_read_b64
// + 12 MFMA -> MFMA:A-byte ratio 4x better than bf16/BN=48 (R6 was L1<-L2
// BW-bound on A re-reads). NO unroll/pipeline: reg budget 128 incl 48 AGPR
// (R2-R5,R8 spilled; WRITE_SIZE is the spill alarm).
__global__ __launch_bounds__(512, 4) void passA(
    const float* __restrict__ Xt, const unsigned char* __restrict__ Asw,
    float* __restrict__ bmin, int fine) {
  __shared__ __align__(16) unsigned char Bs[BN * DIM];  // 73728 B
  __shared__ float t2p[BN][16];
  __shared__ float t2s[BN];
  const int tid = threadIdx.x;
  const int chunk = blockIdx.x;

  // ---- stage: 96 rows -> fp8 LDS (swizzled) + sum-of-squares(quantized) ----
  for (int i = 0; i < 3; ++i) {
    int idx = tid + i * 512;                 // 0..1535 = 96 rows x 16 slices
    int c = idx >> 4, sl = idx & 15;
    int n = chunk * BN + c;
    int base = c * DIM + sl * 48;
    int xm = (c & 15) << 4;                  // XOR after full add; 16B granules
    float ss = 0.f;
    if (n < N_TRAIN) {
      const float* src = Xt + (size_t)n * DIM + sl * 48;
#pragma unroll
      for (int j = 0; j < 3; ++j) {
        f32x4 v0 = *(const f32x4*)(src + j * 16);
        f32x4 v1 = *(const f32x4*)(src + j * 16 + 4);
        f32x4 v2 = *(const f32x4*)(src + j * 16 + 8);
        f32x4 v3 = *(const f32x4*)(src + j * 16 + 12);
        u64 lo = 0, hi = 0;
#pragma unroll
        for (int k = 0; k < 4; ++k) {
          unsigned char b0 = f2q(v0[k]); float d0 = q2f(b0); ss = fmaf(d0, d0, ss);
          lo |= (u64)b0 << (8 * k);
          unsigned char b1 = f2q(v1[k]); float d1 = q2f(b1); ss = fmaf(d1, d1, ss);
          lo |= (u64)b1 << (8 * (k + 4));
          unsigned char b2 = f2q(v2[k]); float d2 = q2f(b2); ss = fmaf(d2, d2, ss);
          hi |= (u64)b2 << (8 * k);
          unsigned char b3 = f2q(v3[k]); float d3 = q2f(b3); ss = fmaf(d3, d3, ss);
          hi |= (u64)b3 << (8 * (k + 4));
        }
        u64x2 w; w[0] = lo; w[1] = hi;
        *(u64x2*)(&Bs[(base + j * 16) ^ xm]) = w;
      }
    } else {
      u64x2 w; w[0] = 0; w[1] = 0;
#pragma unroll
      for (int j = 0; j < 3; ++j) *(u64x2*)(&Bs[(base + j * 16) ^ xm]) = w;
    }
    t2p[c][sl] = ss;
  }
  __syncthreads();
  if (tid < BN) {
    float s = 0.f;
#pragma unroll
    for (int j = 0; j < 16; ++j) s += t2p[tid][j];
    t2s[tid] = (chunk * BN + tid < N_TRAIN) ? s : 3.0e38f;
  }
  __syncthreads();

  const int wid = tid >> 6;
  const int l = tid & 63;
  const int lc = l & 15;
  const int lg = l >> 4;

  int cb[6], xm[6];                          // un-swizzled bases + masks
#pragma unroll
  for (int cf = 0; cf < 6; ++cf) {
    int c = cf * 16 + lc;
    cb[cf] = c * DIM + lg * 8;
    xm[cf] = (c & 15) << 4;
  }

  for (int mt = 0; mt < 4; ++mt) {           // 4 m-tiles of 256 query rows
    f32x4 acc[2][6];
#pragma unroll
    for (int rf = 0; rf < 2; ++rf)
#pragma unroll
      for (int cf = 0; cf < 6; ++cf) {
        acc[rf][cf][0] = 0.f; acc[rf][cf][1] = 0.f;
        acc[rf][cf][2] = 0.f; acc[rf][cf][3] = 0.f;
      }
    const int mfbase = mt * 16 + wid * 2;    // wave owns 32 rows = 2 row-frags
    const unsigned char* ap = Asw + (size_t)mfbase * 24 * 512 + l * 8;

    for (int ks = 0; ks < 24; ++ks) {        // ROLLED (spill!)
      long a0 = *(const long*)(ap + ks * 512);
      long a1 = *(const long*)(ap + (24 + ks) * 512);
      long b[6];
#pragma unroll
      for (int cf = 0; cf < 6; ++cf)
        b[cf] = *(const long*)(&Bs[(cb[cf] + ks * 32) ^ xm[cf]]);
#pragma unroll
      for (int cf = 0; cf < 6; ++cf) {
        acc[0][cf] = __builtin_amdgcn_mfma_f32_16x16x32_fp8_fp8(a0, b[cf], acc[0][cf], 0, 0, 0);
        acc[1][cf] = __builtin_amdgcn_mfma_f32_16x16x32_fp8_fp8(a1, b[cf], acc[1][cf], 0, 0, 0);
      }
    }

    // ---- epilogue: d2' = t2 - 2*cross ; per-row mins; contiguous writes ----
    const int rowbase = mt * 256 + wid * 32;
#pragma unroll
    for (int rf = 0; rf < 2; ++rf) {
#pragma unroll
      for (int reg = 0; reg < 4; ++reg) {
        int row = rowbase + rf * 16 + lg * 4 + reg;
        if (fine) {                           // 6 blocks of 16 cols
#pragma unroll
          for (int cf = 0; cf < 6; ++cf) {
            float v = t2s[cf * 16 + lc] - 2.f * acc[rf][cf][reg];
#pragma unroll
            for (int s = 1; s < 16; s <<= 1) v = fminf(v, __shfl_xor(v, s));
            if (lc == 0)
              bmin[(size_t)chunk * (NQ * 6) + row * 6 + cf] = v;
          }
        } else {                              // one block of 96 cols
          float v = 3.0e38f;
#pragma unroll
          for (int cf = 0; cf < 6; ++cf)
            v = fminf(v, t2s[cf * 16 + lc] - 2.f * acc[rf][cf][reg]);
#pragma unroll
          for (int s = 1; s < 16; s <<= 1) v = fminf(v, __shfl_xor(v, s));
          if (lc == 0)
            bmin[(size_t)chunk * NQ + row] = v;
        }
      }
    }
  }
}

// ------- Pass B1: per-query global min (coalesced over q, atomicMin) -------
__global__ __launch_bounds__(256) void passB1(const float* __restrict__ bmin,
                                              unsigned int* __restrict__ gmin, int bpq) {
  int qg = blockIdx.x >> 4, cs = blockIdx.x & 15;
  int w = threadIdx.x >> 6, l = threadIdx.x & 63;
  int q = qg * 64 + l;
  float m = 3.0e38f;
  for (int j = cs * 4 + w; j < NCHUNK; j += 64) {
    const float* p = bmin + (size_t)j * (NQ * bpq) + q * bpq;
    for (int cf = 0; cf < bpq; ++cf) m = fminf(m, p[cf]);
  }
  __shared__ float sm[4][64];
  sm[w][l] = m;
  __syncthreads();
  if (threadIdx.x < 64) {
    float v = fminf(fminf(sm[0][l], sm[1][l]), fminf(sm[2][l], sm[3][l]));
    atomicMin(&gmin[q], fenc(v));
  }
}

// ------- Pass B2: emit candidate blocks within min+MARGIN -------
__global__ __launch_bounds__(256) void passB2(const float* __restrict__ bmin,
                                              const unsigned int* __restrict__ gmin,
                                              unsigned int* __restrict__ cnt,
                                              unsigned int* __restrict__ cand, int bpq) {
  int qg = blockIdx.x >> 4, cs = blockIdx.x & 15;
  int w = threadIdx.x >> 6, l = threadIdx.x & 63;
  int q = qg * 64 + l;
  float thr = fdec(gmin[q]) + MARGIN;
  for (int j = cs * 4 + w; j < NCHUNK; j += 64) {
    const float* p = bmin + (size_t)j * (NQ * bpq) + q * bpq;
    for (int cf = 0; cf < bpq; ++cf) {
      if (p[cf] <= thr) {
        unsigned int pos = atomicAdd(cnt, 1u);
        if (pos < MAXC) cand[pos] = ((unsigned int)q << 16) | (unsigned int)(j * bpq + cf);
      }
    }
  }
}

// ---------------- Pass C: exact fp32 re-rank of candidates ----------------
__global__ void passC(const float* __restrict__ x, const float* __restrict__ Xt,
                      const unsigned int* __restrict__ cnt, const unsigned int* __restrict__ cand,
                      unsigned long long* __restrict__ res, int cpbsh, int ncols) {
  unsigned int count = *cnt;
  if (count > MAXC) count = MAXC;
  int w = threadIdx.x >> 6, l = threadIdx.x & 63;
  long pairs = (long)count << cpbsh;
  for (long p = (long)blockIdx.x * 4 + w; p < pairs; p += (long)gridDim.x * 4) {
    unsigned int cd = cand[p >> cpbsh];
    int q = cd >> 16;
    int blk = cd & 0xFFFF;
    int col = (int)(p & ((1 << cpbsh) - 1));
    int n = blk * ncols + col;
    if (col >= ncols || n >= N_TRAIN) continue;   // wave-uniform
    const float* xq = x + (size_t)q * DIM;
    const float* tn = Xt + (size_t)n * DIM;
    float s = 0.f;
#pragma unroll
    for (int i = 0; i < 12; ++i) {
      float d = xq[i * 64 + l] - tn[i * 64 + l];
      s = fmaf(d, d, s);
    }
#pragma unroll
    for (int sh = 1; sh < 64; sh <<= 1) s += __shfl_xor(s, sh);
    if (l == 0) {
      unsigned long long key =
          ((unsigned long long)__builtin_bit_cast(unsigned int, s) << 32) | (unsigned int)n;
      atomicMin(res + q, key);                // min d2, tie -> lowest index
    }
  }
}

// ---------------- Pass D: gather ----------------
__global__ void passD(const unsigned long long* __restrict__ res,
                      const float* __restrict__ Y, float* __restrict__ out) {
  int t = blockIdx.x * 256 + threadIdx.x;
  if (t < NQ * 24) {
    int q = t / 24, j = t - q * 24;
    unsigned int idx = (unsigned int)(res[q] & 0xFFFFFFFFu);
    out[t] = Y[(size_t)idx * 24 + j];
  }
}

extern "C" void kernel_launch(void* const* d_in, const int* in_sizes, int n_in,
                              void* d_out, int out_size, void* d_ws, size_t ws_size,
                              hipStream_t stream) {
  const float* x  = (const float*)d_in[0];   // [1024][768]
  const float* Xt = (const float*)d_in[1];   // [100000][768]
  const float* Y  = (const float*)d_in[2];   // [100000][24]
  float* out = (float*)d_out;                // [1024*24]
  char* ws = (char*)d_ws;
  unsigned long long* res  = (unsigned long long*)(ws);        // 8192 B
  unsigned int*       cnt  = (unsigned int*)(ws + 8192);       // 256 B
  unsigned int*       gmin = (unsigned int*)(ws + 8448);       // 4096 B
  unsigned int*       cand = (unsigned int*)(ws + 12544);      // 256 KB
  unsigned char*      Asw  = (unsigned char*)(ws + 274688);    // 768 KB
  float*              bmin = (float*)(ws + 1061120);           // 25.6 / 4.3 MB

  size_t needFine = 1061120ull + (size_t)NCHUNK * NQ * 6 * 4ull;  // ~26.7 MB
  int fine, bpq, cpbsh, ncols;
  if (ws_size >= needFine) { fine = 1; bpq = 6; cpbsh = 4; ncols = 16; }
  else                     { fine = 0; bpq = 1; cpbsh = 7; ncols = 96; }

  hipLaunchKernelGGL(initK,  dim3(1),      dim3(1024), 0, stream, res, gmin, cnt);
  hipLaunchKernelGGL(convA,  dim3(384),    dim3(256),  0, stream, x, Asw);
  hipLaunchKernelGGL(passA,  dim3(NCHUNK), dim3(512),  0, stream, Xt, Asw, bmin, fine);
  hipLaunchKernelGGL(passB1, dim3(256),    dim3(256),  0, stream, bmin, gmin, bpq);
  hipLaunchKernelGGL(passB2, dim3(256),    dim3(256),  0, stream, bmin, gmin, cnt, cand, bpq);
  hipLaunchKernelGGL(passC,  dim3(512),    dim3(256),  0, stream, x, Xt, cnt, cand, res, cpbsh, ncols);
  hipLaunchKernelGGL(passD,  dim3(96),     dim3(256),  0, stream, res, Y, out);
}